// Round 2
// baseline (10558.188 us; speedup 1.0000x reference)
//
#include <hip/hip_runtime.h>
#include <hip/hip_bf16.h>
#include <stdint.h>

// Problem constants
#define B_  4
#define S_  2048
#define D_  1024
#define H_  16
#define DH_ 64
#define N3_ 3072   // 3*D

// I/O dtypes (per reference): x, w_qkv, b_qkv, w_out, b_out, out = float32.
// mask = int32. Intermediates (q,k,v,ctx) stored bf16 in workspace, fp32 math.

__device__ __forceinline__ float bf2f(unsigned short u) {
    union { unsigned int i; float f; } c; c.i = ((unsigned int)u) << 16; return c.f;
}
__device__ __forceinline__ unsigned short f2bf(float f) {
    union { float f; unsigned int i; } c; c.f = f;
    unsigned int x = c.i;
    return (unsigned short)((x + 0x7FFFu + ((x >> 16) & 1u)) >> 16);  // RNE
}

// ---------------------------------------------------------------------------
// QKV projection: X(8192,1024)fp32 @ Wqkv(1024,3072)fp32 + b -> scatter to
// Q/K/V stored [B][H][S][DH] bf16. 32x32 tile, 256 threads, 2x2 per thread.
// ---------------------------------------------------------------------------
__global__ __launch_bounds__(256) void qkv_gemm(
    const float* __restrict__ x, const float* __restrict__ w,
    const float* __restrict__ bias,
    unsigned short* __restrict__ q, unsigned short* __restrict__ k,
    unsigned short* __restrict__ v)
{
    __shared__ float As[32][33];
    __shared__ float Bs[32][33];
    const int tid = threadIdx.x;
    const int tx = tid & 15, ty = tid >> 4;
    const int m0 = blockIdx.y * 32;
    const int n0 = blockIdx.x * 32;
    const int lr = tid >> 3;          // staging row 0..31
    const int lc = (tid & 7) * 4;     // staging col (x4 floats)
    float a00 = 0.f, a01 = 0.f, a10 = 0.f, a11 = 0.f;

    for (int kt = 0; kt < D_; kt += 32) {
        float4 av = *(const float4*)(x + (size_t)(m0 + lr) * D_ + kt + lc);
        float4 bv = *(const float4*)(w + (size_t)(kt + lr) * N3_ + n0 + lc);
        As[lr][lc + 0] = av.x; As[lr][lc + 1] = av.y;
        As[lr][lc + 2] = av.z; As[lr][lc + 3] = av.w;
        Bs[lr][lc + 0] = bv.x; Bs[lr][lc + 1] = bv.y;
        Bs[lr][lc + 2] = bv.z; Bs[lr][lc + 3] = bv.w;
        __syncthreads();
#pragma unroll
        for (int kk = 0; kk < 32; ++kk) {
            float va0 = As[ty * 2 + 0][kk];
            float va1 = As[ty * 2 + 1][kk];
            float vb0 = Bs[kk][tx * 2 + 0];
            float vb1 = Bs[kk][tx * 2 + 1];
            a00 += va0 * vb0; a01 += va0 * vb1;
            a10 += va1 * vb0; a11 += va1 * vb1;
        }
        __syncthreads();
    }

    float accs[2][2] = {{a00, a01}, {a10, a11}};
#pragma unroll
    for (int i = 0; i < 2; ++i) {
#pragma unroll
        for (int j = 0; j < 2; ++j) {
            int m = m0 + ty * 2 + i;
            int n = n0 + tx * 2 + j;
            float val = accs[i][j] + bias[n];
            int which = n >> 10;          // 0=Q 1=K 2=V
            int h  = (n & 1023) >> 6;
            int dh = n & 63;
            int bb = m >> 11;
            int s  = m & 2047;
            size_t off = (((size_t)bb * H_ + h) * S_ + s) * DH_ + dh;
            unsigned short* dst = (which == 0) ? q : ((which == 1) ? k : v);
            dst[off] = f2bf(val);
        }
    }
}

// ---------------------------------------------------------------------------
// Attention: one block (256 thr) per (b, h, q-row). Scores in LDS (fp32),
// mask==0 -> -1000 (after 1/sqrt(DH) scale, matching reference), softmax,
// then PV with coalesced V reads (lane = dh).
// ---------------------------------------------------------------------------
__global__ __launch_bounds__(256) void attn(
    const unsigned short* __restrict__ q, const unsigned short* __restrict__ k,
    const unsigned short* __restrict__ v, const int* __restrict__ mask,
    unsigned short* __restrict__ ctx)
{
    __shared__ float qs[DH_];
    __shared__ float sc[S_];
    __shared__ float red[256];
    const int tid  = threadIdx.x;
    const int qrow = blockIdx.x;
    const int h    = blockIdx.y;
    const int bb   = blockIdx.z;
    const int bh   = bb * H_ + h;
    const size_t kvbase = (size_t)bh * S_ * DH_;

    if (tid < DH_) qs[tid] = bf2f(q[kvbase + (size_t)qrow * DH_ + tid]);
    __syncthreads();

    const size_t mbase = ((size_t)bb * S_ + qrow) * S_;
    float lmax = -3.4e38f;
#pragma unroll
    for (int j = 0; j < S_ / 256; ++j) {
        int kk = tid + j * 256;
        const ushort4* kp = (const ushort4*)(k + kvbase + (size_t)kk * DH_);
        float s = 0.f;
#pragma unroll
        for (int i = 0; i < DH_ / 4; ++i) {
            ushort4 u = kp[i];
            s += qs[i * 4 + 0] * bf2f(u.x) + qs[i * 4 + 1] * bf2f(u.y)
               + qs[i * 4 + 2] * bf2f(u.z) + qs[i * 4 + 3] * bf2f(u.w);
        }
        s *= 0.125f;                       // 1/sqrt(64)
        if (mask[mbase + kk] == 0) s = -1000.0f;
        sc[kk] = s;
        lmax = fmaxf(lmax, s);
    }
    red[tid] = lmax; __syncthreads();
    for (int off = 128; off > 0; off >>= 1) {
        if (tid < off) red[tid] = fmaxf(red[tid], red[tid + off]);
        __syncthreads();
    }
    float gmax = red[0]; __syncthreads();

    float lsum = 0.f;
#pragma unroll
    for (int j = 0; j < S_ / 256; ++j) {
        int kk = tid + j * 256;
        float p = __expf(sc[kk] - gmax);
        sc[kk] = p;
        lsum += p;
    }
    red[tid] = lsum; __syncthreads();
    for (int off = 128; off > 0; off >>= 1) {
        if (tid < off) red[tid] += red[tid + off];
        __syncthreads();
    }
    float inv = 1.0f / red[0];
    __syncthreads();

    const int d = tid & 63, g = tid >> 6;   // 4 groups of 64 lanes
    float acc = 0.f;
    for (int i = 0; i < S_ / 4; ++i) {
        int kk = g * (S_ / 4) + i;
        acc += sc[kk] * bf2f(v[kvbase + (size_t)kk * DH_ + d]);
    }
    red[tid] = acc; __syncthreads();
    if (tid < DH_) {
        float total = (red[tid] + red[tid + 64]) + (red[tid + 128] + red[tid + 192]);
        ctx[((size_t)bb * S_ + qrow) * D_ + h * DH_ + d] = f2bf(total * inv);
    }
}

// ---------------------------------------------------------------------------
// Output projection: ctx(8192,1024)bf16 @ Wout(1024,1024)fp32 + b -> out fp32
// ---------------------------------------------------------------------------
__global__ __launch_bounds__(256) void out_gemm(
    const unsigned short* __restrict__ ctx, const float* __restrict__ w,
    const float* __restrict__ bias, float* __restrict__ out)
{
    __shared__ float As[32][33];
    __shared__ float Bs[32][33];
    const int tid = threadIdx.x;
    const int tx = tid & 15, ty = tid >> 4;
    const int m0 = blockIdx.y * 32;
    const int n0 = blockIdx.x * 32;
    const int lr = tid >> 3;
    const int lc = (tid & 7) * 4;
    float a00 = 0.f, a01 = 0.f, a10 = 0.f, a11 = 0.f;

    for (int kt = 0; kt < D_; kt += 32) {
        ushort4 av = *(const ushort4*)(ctx + (size_t)(m0 + lr) * D_ + kt + lc);
        float4 bv = *(const float4*)(w + (size_t)(kt + lr) * D_ + n0 + lc);
        As[lr][lc + 0] = bf2f(av.x); As[lr][lc + 1] = bf2f(av.y);
        As[lr][lc + 2] = bf2f(av.z); As[lr][lc + 3] = bf2f(av.w);
        Bs[lr][lc + 0] = bv.x; Bs[lr][lc + 1] = bv.y;
        Bs[lr][lc + 2] = bv.z; Bs[lr][lc + 3] = bv.w;
        __syncthreads();
#pragma unroll
        for (int kk = 0; kk < 32; ++kk) {
            float va0 = As[ty * 2 + 0][kk];
            float va1 = As[ty * 2 + 1][kk];
            float vb0 = Bs[kk][tx * 2 + 0];
            float vb1 = Bs[kk][tx * 2 + 1];
            a00 += va0 * vb0; a01 += va0 * vb1;
            a10 += va1 * vb0; a11 += va1 * vb1;
        }
        __syncthreads();
    }

    float accs[2][2] = {{a00, a01}, {a10, a11}};
#pragma unroll
    for (int i = 0; i < 2; ++i) {
#pragma unroll
        for (int j = 0; j < 2; ++j) {
            int m = m0 + ty * 2 + i;
            int n = n0 + tx * 2 + j;
            out[(size_t)m * D_ + n] = accs[i][j] + bias[n];
        }
    }
}

extern "C" void kernel_launch(void* const* d_in, const int* in_sizes, int n_in,
                              void* d_out, int out_size, void* d_ws, size_t ws_size,
                              hipStream_t stream)
{
    const float* x     = (const float*)d_in[0];
    const int*   mask  = (const int*)d_in[1];
    const float* w_qkv = (const float*)d_in[2];
    const float* b_qkv = (const float*)d_in[3];
    const float* w_out = (const float*)d_in[4];
    const float* b_out = (const float*)d_in[5];
    float* out = (float*)d_out;

    unsigned short* ws = (unsigned short*)d_ws;
    const size_t sz = (size_t)B_ * S_ * D_;   // 8,388,608 elements
    unsigned short* q   = ws;
    unsigned short* k   = ws + sz;
    unsigned short* v   = ws + 2 * sz;
    unsigned short* ctx = ws + 3 * sz;

    qkv_gemm<<<dim3(N3_ / 32, (B_ * S_) / 32), 256, 0, stream>>>(x, w_qkv, b_qkv, q, k, v);
    attn<<<dim3(S_, H_, B_), 256, 0, stream>>>(q, k, v, mask, ctx);
    out_gemm<<<dim3(D_ / 32, (B_ * S_) / 32), 256, 0, stream>>>(ctx, w_out, b_out, out);
}

// Round 3
// 2408.978 us; speedup vs baseline: 4.3829x; 4.3829x over previous
//
#include <hip/hip_runtime.h>
#include <hip/hip_bf16.h>
#include <stdint.h>

// Problem constants
#define B_  4
#define S_  2048
#define D_  1024
#define H_  16
#define DH_ 64
#define N3_ 3072   // 3*D

typedef __attribute__((ext_vector_type(8))) short  short8;   // 8 bf16 (4 VGPRs)
typedef __attribute__((ext_vector_type(4))) float  float4v;  // 4 fp32 acc

__device__ __forceinline__ float bf2f(unsigned short u) {
    union { unsigned int i; float f; } c; c.i = ((unsigned int)u) << 16; return c.f;
}
__device__ __forceinline__ unsigned short f2bf(float f) {
    union { float f; unsigned int i; } c; c.f = f;
    unsigned int x = c.i;
    return (unsigned short)((x + 0x7FFFu + ((x >> 16) & 1u)) >> 16);  // RNE
}

// ---------------------------------------------------------------------------
// QKV projection: X(8192,1024)fp32 @ Wqkv(1024,3072)fp32 + b -> scatter to
// Q/K/V stored [B][H][S][DH] bf16. 32x32 tile, 256 threads, 2x2 per thread.
// ---------------------------------------------------------------------------
__global__ __launch_bounds__(256) void qkv_gemm(
    const float* __restrict__ x, const float* __restrict__ w,
    const float* __restrict__ bias,
    unsigned short* __restrict__ q, unsigned short* __restrict__ k,
    unsigned short* __restrict__ v)
{
    __shared__ float As[32][33];
    __shared__ float Bs[32][33];
    const int tid = threadIdx.x;
    const int tx = tid & 15, ty = tid >> 4;
    const int m0 = blockIdx.y * 32;
    const int n0 = blockIdx.x * 32;
    const int lr = tid >> 3;          // staging row 0..31
    const int lc = (tid & 7) * 4;     // staging col (x4 floats)
    float a00 = 0.f, a01 = 0.f, a10 = 0.f, a11 = 0.f;

    for (int kt = 0; kt < D_; kt += 32) {
        float4 av = *(const float4*)(x + (size_t)(m0 + lr) * D_ + kt + lc);
        float4 bv = *(const float4*)(w + (size_t)(kt + lr) * N3_ + n0 + lc);
        As[lr][lc + 0] = av.x; As[lr][lc + 1] = av.y;
        As[lr][lc + 2] = av.z; As[lr][lc + 3] = av.w;
        Bs[lr][lc + 0] = bv.x; Bs[lr][lc + 1] = bv.y;
        Bs[lr][lc + 2] = bv.z; Bs[lr][lc + 3] = bv.w;
        __syncthreads();
#pragma unroll
        for (int kk = 0; kk < 32; ++kk) {
            float va0 = As[ty * 2 + 0][kk];
            float va1 = As[ty * 2 + 1][kk];
            float vb0 = Bs[kk][tx * 2 + 0];
            float vb1 = Bs[kk][tx * 2 + 1];
            a00 += va0 * vb0; a01 += va0 * vb1;
            a10 += va1 * vb0; a11 += va1 * vb1;
        }
        __syncthreads();
    }

    float accs[2][2] = {{a00, a01}, {a10, a11}};
#pragma unroll
    for (int i = 0; i < 2; ++i) {
#pragma unroll
        for (int j = 0; j < 2; ++j) {
            int m = m0 + ty * 2 + i;
            int n = n0 + tx * 2 + j;
            float val = accs[i][j] + bias[n];
            int which = n >> 10;          // 0=Q 1=K 2=V
            int h  = (n & 1023) >> 6;
            int dh = n & 63;
            int bb = m >> 11;
            int s  = m & 2047;
            size_t off = (((size_t)bb * H_ + h) * S_ + s) * DH_ + dh;
            unsigned short* dst = (which == 0) ? q : ((which == 1) ? k : v);
            dst[off] = f2bf(val);
        }
    }
}

// ---------------------------------------------------------------------------
// Flash-style MFMA attention.
// Block = 256 thr (4 waves) handles 64 q-rows of one (b,h); wave owns 16 rows.
// K-loop over 64-key tiles: stage K [key][dh] and V^T [dh][key] in LDS,
// QK^T via mfma_f32_16x16x32_bf16, online softmax in regs (shfl over 16-lane
// col groups), P -> LDS (A-layout round trip), PV via MFMA with V^T B-frags.
// Fragment layouts (m89/m91/m120-verified):
//   A[m][k]: m=lane&15, k=quad*8+j   (quad=lane>>4, j=0..7)
//   B[k][n]: n=lane&15, k=quad*8+j
//   C/D   : col=lane&15, row=quad*4+reg
// ---------------------------------------------------------------------------
__global__ __launch_bounds__(256) void attn_mfma(
    const unsigned short* __restrict__ q, const unsigned short* __restrict__ k,
    const unsigned short* __restrict__ v, const int* __restrict__ mask,
    unsigned short* __restrict__ ctx)
{
    __shared__ unsigned short Ks[64][72];      // [key][dh], pad 64->72 (2-way max)
    __shared__ unsigned short Vt[64][72];      // [dh][key], pad
    __shared__ unsigned short Ps[4][16][72];   // per-wave P tile [qrow][key]

    const int tid  = threadIdx.x;
    const int wave = tid >> 6;
    const int lane = tid & 63;
    const int col  = lane & 15;     // n / col index
    const int quad = lane >> 4;     // 0..3

    const int h  = blockIdx.y;
    const int bb = blockIdx.z;
    const int q0 = blockIdx.x * 64 + wave * 16;   // this wave's 16 q-rows
    const size_t kvbase = ((size_t)bb * H_ + h) * S_ * DH_;

    // Q A-frags (held for whole kernel): rows q0+col, dh = step*32 + quad*8 + j
    const unsigned short* qrow = q + kvbase + (size_t)(q0 + col) * DH_;
    short8 qa0 = *(const short8*)(qrow + quad * 8);
    short8 qa1 = *(const short8*)(qrow + 32 + quad * 8);

    // mask row bases for this lane's 4 C-rows (q = q0 + quad*4 + reg)
    size_t mrow[4];
#pragma unroll
    for (int r = 0; r < 4; ++r)
        mrow[r] = ((size_t)bb * S_ + (q0 + quad * 4 + r)) * (size_t)S_;

    float4v oacc[4] = {};            // O accumulator: 4 n-steps x 4 rows
    float m_run[4] = {-3.0e38f, -3.0e38f, -3.0e38f, -3.0e38f};
    float l_run[4] = {0.f, 0.f, 0.f, 0.f};

    for (int kt = 0; kt < S_ / 64; ++kt) {
        const int key0 = kt * 64;

        // ---- stage K tile and V^T tile (coalesced global loads) ----
#pragma unroll
        for (int i = 0; i < 4; ++i) {
            int idx = tid + i * 256;
            int r  = idx >> 4;             // 0..63 (key)
            int c4 = (idx & 15) * 4;       // dh group of 4
            ushort4 gk = *(const ushort4*)(k + kvbase + (size_t)(key0 + r) * DH_ + c4);
            *(ushort4*)&Ks[r][c4] = gk;
            ushort4 gv = *(const ushort4*)(v + kvbase + (size_t)(key0 + r) * DH_ + c4);
            Vt[c4 + 0][r] = gv.x; Vt[c4 + 1][r] = gv.y;
            Vt[c4 + 2][r] = gv.z; Vt[c4 + 3][r] = gv.w;
        }
        __syncthreads();

        // ---- QK^T: 4 key-subtiles of 16, k-dim 64 = 2 MFMAs ----
        float4v sc[4];
#pragma unroll
        for (int sub = 0; sub < 4; ++sub) {
            short8 b0 = *(const short8*)&Ks[sub * 16 + col][quad * 8];
            short8 b1 = *(const short8*)&Ks[sub * 16 + col][32 + quad * 8];
            float4v a = {};
            a = __builtin_amdgcn_mfma_f32_16x16x32_bf16(qa0, b0, a, 0, 0, 0);
            a = __builtin_amdgcn_mfma_f32_16x16x32_bf16(qa1, b1, a, 0, 0, 0);
            sc[sub] = a;
        }

        // ---- scale + mask ----
#pragma unroll
        for (int sub = 0; sub < 4; ++sub) {
#pragma unroll
            for (int r = 0; r < 4; ++r) {
                float s = sc[sub][r] * 0.125f;     // 1/sqrt(64)
                int mk = mask[mrow[r] + key0 + sub * 16 + col];
                sc[sub][r] = (mk == 0) ? -1000.0f : s;
            }
        }

        // ---- online softmax: row stats over this 64-key tile ----
        float tmax[4];
#pragma unroll
        for (int r = 0; r < 4; ++r) {
            tmax[r] = fmaxf(fmaxf(sc[0][r], sc[1][r]), fmaxf(sc[2][r], sc[3][r]));
#pragma unroll
            for (int msk = 1; msk < 16; msk <<= 1)
                tmax[r] = fmaxf(tmax[r], __shfl_xor(tmax[r], msk));
        }
        float alpha[4], rsum[4];
#pragma unroll
        for (int r = 0; r < 4; ++r) {
            float mn = fmaxf(m_run[r], tmax[r]);
            alpha[r] = __expf(m_run[r] - mn);
            m_run[r] = mn;
            rsum[r] = 0.f;
        }
        // P = exp(s - m), write to LDS in A-layout source order
#pragma unroll
        for (int sub = 0; sub < 4; ++sub) {
#pragma unroll
            for (int r = 0; r < 4; ++r) {
                float p = __expf(sc[sub][r] - m_run[r]);
                rsum[r] += p;
                Ps[wave][quad * 4 + r][sub * 16 + col] = f2bf(p);
            }
        }
#pragma unroll
        for (int r = 0; r < 4; ++r) {
#pragma unroll
            for (int msk = 1; msk < 16; msk <<= 1)
                rsum[r] += __shfl_xor(rsum[r], msk);
            l_run[r] = l_run[r] * alpha[r] + rsum[r];
        }
        // rescale O accumulator
#pragma unroll
        for (int n = 0; n < 4; ++n)
#pragma unroll
            for (int r = 0; r < 4; ++r)
                oacc[n][r] *= alpha[r];

        __syncthreads();   // P visible (barrier also orders Ks reads vs restage)

        // ---- PV: O(16x64) += P(16x64) * V(64x64) ----
#pragma unroll
        for (int n = 0; n < 4; ++n) {
#pragma unroll
            for (int kk = 0; kk < 2; ++kk) {
                short8 pa = *(const short8*)&Ps[wave][col][kk * 32 + quad * 8];
                short8 vb = *(const short8*)&Vt[n * 16 + col][kk * 32 + quad * 8];
                oacc[n] = __builtin_amdgcn_mfma_f32_16x16x32_bf16(pa, vb, oacc[n], 0, 0, 0);
            }
        }
        __syncthreads();   // Vt/Ps reads done before next restage
    }

    // ---- epilogue: O / l -> ctx [b][s][h*64+dh] bf16 ----
    float inv[4];
#pragma unroll
    for (int r = 0; r < 4; ++r) inv[r] = 1.0f / l_run[r];
#pragma unroll
    for (int n = 0; n < 4; ++n) {
#pragma unroll
        for (int r = 0; r < 4; ++r) {
            size_t off = ((size_t)bb * S_ + (q0 + quad * 4 + r)) * D_
                       + h * DH_ + n * 16 + col;
            ctx[off] = f2bf(oacc[n][r] * inv[r]);
        }
    }
}

// ---------------------------------------------------------------------------
// Output projection: ctx(8192,1024)bf16 @ Wout(1024,1024)fp32 + b -> out fp32
// ---------------------------------------------------------------------------
__global__ __launch_bounds__(256) void out_gemm(
    const unsigned short* __restrict__ ctx, const float* __restrict__ w,
    const float* __restrict__ bias, float* __restrict__ out)
{
    __shared__ float As[32][33];
    __shared__ float Bs[32][33];
    const int tid = threadIdx.x;
    const int tx = tid & 15, ty = tid >> 4;
    const int m0 = blockIdx.y * 32;
    const int n0 = blockIdx.x * 32;
    const int lr = tid >> 3;
    const int lc = (tid & 7) * 4;
    float a00 = 0.f, a01 = 0.f, a10 = 0.f, a11 = 0.f;

    for (int kt = 0; kt < D_; kt += 32) {
        ushort4 av = *(const ushort4*)(ctx + (size_t)(m0 + lr) * D_ + kt + lc);
        float4 bv = *(const float4*)(w + (size_t)(kt + lr) * D_ + n0 + lc);
        As[lr][lc + 0] = bf2f(av.x); As[lr][lc + 1] = bf2f(av.y);
        As[lr][lc + 2] = bf2f(av.z); As[lr][lc + 3] = bf2f(av.w);
        Bs[lr][lc + 0] = bv.x; Bs[lr][lc + 1] = bv.y;
        Bs[lr][lc + 2] = bv.z; Bs[lr][lc + 3] = bv.w;
        __syncthreads();
#pragma unroll
        for (int kk = 0; kk < 32; ++kk) {
            float va0 = As[ty * 2 + 0][kk];
            float va1 = As[ty * 2 + 1][kk];
            float vb0 = Bs[kk][tx * 2 + 0];
            float vb1 = Bs[kk][tx * 2 + 1];
            a00 += va0 * vb0; a01 += va0 * vb1;
            a10 += va1 * vb0; a11 += va1 * vb1;
        }
        __syncthreads();
    }

    float accs[2][2] = {{a00, a01}, {a10, a11}};
#pragma unroll
    for (int i = 0; i < 2; ++i) {
#pragma unroll
        for (int j = 0; j < 2; ++j) {
            int m = m0 + ty * 2 + i;
            int n = n0 + tx * 2 + j;
            out[(size_t)m * D_ + n] = accs[i][j] + bias[n];
        }
    }
}

extern "C" void kernel_launch(void* const* d_in, const int* in_sizes, int n_in,
                              void* d_out, int out_size, void* d_ws, size_t ws_size,
                              hipStream_t stream)
{
    const float* x     = (const float*)d_in[0];
    const int*   mask  = (const int*)d_in[1];
    const float* w_qkv = (const float*)d_in[2];
    const float* b_qkv = (const float*)d_in[3];
    const float* w_out = (const float*)d_in[4];
    const float* b_out = (const float*)d_in[5];
    float* out = (float*)d_out;

    unsigned short* ws = (unsigned short*)d_ws;
    const size_t sz = (size_t)B_ * S_ * D_;   // 8,388,608 elements
    unsigned short* q   = ws;
    unsigned short* k   = ws + sz;
    unsigned short* v   = ws + 2 * sz;
    unsigned short* ctx = ws + 3 * sz;

    qkv_gemm<<<dim3(N3_ / 32, (B_ * S_) / 32), 256, 0, stream>>>(x, w_qkv, b_qkv, q, k, v);
    attn_mfma<<<dim3(S_ / 64, H_, B_), 256, 0, stream>>>(q, k, v, mask, ctx);
    out_gemm<<<dim3(D_ / 32, (B_ * S_) / 32), 256, 0, stream>>>(ctx, w_out, b_out, out);
}

// Round 4
// 553.819 us; speedup vs baseline: 19.0643x; 4.3498x over previous
//
#include <hip/hip_runtime.h>
#include <hip/hip_bf16.h>
#include <stdint.h>

// Problem constants
#define B_  4
#define S_  2048
#define D_  1024
#define H_  16
#define DH_ 64
#define N3_ 3072   // 3*D

typedef __attribute__((ext_vector_type(8))) short  short8;   // 8 bf16 (4 VGPRs)
typedef __attribute__((ext_vector_type(8))) unsigned short ushort8;
typedef __attribute__((ext_vector_type(4))) float  float4v;  // 4 fp32 acc

__device__ __forceinline__ float bf2f(unsigned short u) {
    union { unsigned int i; float f; } c; c.i = ((unsigned int)u) << 16; return c.f;
}
__device__ __forceinline__ unsigned short f2bf(float f) {
    union { float f; unsigned int i; } c; c.f = f;
    unsigned int x = c.i;
    return (unsigned short)((x + 0x7FFFu + ((x >> 16) & 1u)) >> 16);  // RNE
}

// ---------------------------------------------------------------------------
// fp32 -> bf16 elementwise (x). 8 elems/thread.
// ---------------------------------------------------------------------------
__global__ __launch_bounds__(256) void convert_x(
    const float* __restrict__ in, unsigned short* __restrict__ out, int n8)
{
    int g = blockIdx.x * 256 + threadIdx.x;
    if (g >= n8) return;
    const float4* p = (const float4*)(in + (size_t)g * 8);
    float4 a = p[0], b = p[1];
    ushort8 o;
    o[0] = f2bf(a.x); o[1] = f2bf(a.y); o[2] = f2bf(a.z); o[3] = f2bf(a.w);
    o[4] = f2bf(b.x); o[5] = f2bf(b.y); o[6] = f2bf(b.z); o[7] = f2bf(b.w);
    *(ushort8*)(out + (size_t)g * 8) = o;
}

// ---------------------------------------------------------------------------
// fp32 [K][N] -> bf16 [N][K] transpose (weights). 32x32 LDS tile, 256 thr.
// ---------------------------------------------------------------------------
__global__ __launch_bounds__(256) void convert_wT(
    const float* __restrict__ w, unsigned short* __restrict__ wt, int K, int N)
{
    __shared__ float t[32][33];
    const int row = threadIdx.x >> 5;   // 0..7
    const int col = threadIdx.x & 31;   // 0..31
    const int n0 = blockIdx.x * 32;
    const int k0 = blockIdx.y * 32;
#pragma unroll
    for (int i = 0; i < 4; ++i)
        t[row + 8 * i][col] = w[(size_t)(k0 + row + 8 * i) * N + n0 + col];
    __syncthreads();
#pragma unroll
    for (int i = 0; i < 4; ++i)
        wt[(size_t)(n0 + row + 8 * i) * K + k0 + col] = f2bf(t[col][row + 8 * i]);
}

// ---------------------------------------------------------------------------
// bf16 MFMA GEMM: C[M,N] = A[M,K] @ Bt[N,K]^T + bias.
// 128x128 tile, BK=64, 256 thr = 4 waves, each wave 64x64 (4x4 MFMA tiles).
// MODE 0: scatter to q/k/v [B][H][S][DH] bf16 (N=3072).
// MODE 1: fp32 out [M][N] (N=1024).
// Fragment layouts as validated by attn_mfma (round 3):
//   A[m][k]: m=lane&15, k=quad*8+j ; B[k][n]: n=lane&15, k=quad*8+j
//   C/D    : col(n)=lane&15, row(m)=quad*4+reg
// ---------------------------------------------------------------------------
template <int MODE>
__global__ __launch_bounds__(256) void gemm_bt(
    const unsigned short* __restrict__ a, const unsigned short* __restrict__ bt,
    const float* __restrict__ bias,
    unsigned short* __restrict__ q, unsigned short* __restrict__ k,
    unsigned short* __restrict__ v, float* __restrict__ out,
    int K, int N)
{
    __shared__ unsigned short As[128][72];   // pad 64->72 (16B-aligned rows)
    __shared__ unsigned short Bs[128][72];

    const int tid  = threadIdx.x;
    const int wave = tid >> 6;
    const int lane = tid & 63;
    const int col  = lane & 15;
    const int quad = lane >> 4;
    const int wm   = (wave & 1) * 64;   // wave m-offset in tile
    const int wn   = (wave >> 1) * 64;  // wave n-offset in tile

    const int m0 = blockIdx.y * 128;
    const int n0 = blockIdx.x * 128;

    float4v acc[4][4] = {};

    for (int kt = 0; kt < K; kt += 64) {
        // stage A and Bt tiles: 8192 bf16 each, 4 x ushort8 per thread
#pragma unroll
        for (int i = 0; i < 4; ++i) {
            int g = tid + i * 256;
            int r = g >> 3;
            int c8 = (g & 7) * 8;
            *(ushort8*)&As[r][c8] = *(const ushort8*)(a  + (size_t)(m0 + r) * K + kt + c8);
            *(ushort8*)&Bs[r][c8] = *(const ushort8*)(bt + (size_t)(n0 + r) * K + kt + c8);
        }
        __syncthreads();

#pragma unroll
        for (int ks = 0; ks < 64; ks += 32) {
            short8 af[4], bf[4];
#pragma unroll
            for (int mi = 0; mi < 4; ++mi)
                af[mi] = *(const short8*)&As[wm + mi * 16 + col][ks + quad * 8];
#pragma unroll
            for (int ni = 0; ni < 4; ++ni)
                bf[ni] = *(const short8*)&Bs[wn + ni * 16 + col][ks + quad * 8];
#pragma unroll
            for (int mi = 0; mi < 4; ++mi)
#pragma unroll
                for (int ni = 0; ni < 4; ++ni)
                    acc[mi][ni] = __builtin_amdgcn_mfma_f32_16x16x32_bf16(
                        af[mi], bf[ni], acc[mi][ni], 0, 0, 0);
        }
        __syncthreads();
    }

    // epilogue
#pragma unroll
    for (int mi = 0; mi < 4; ++mi) {
#pragma unroll
        for (int ni = 0; ni < 4; ++ni) {
            int n = n0 + wn + ni * 16 + col;
            float bv = bias[n];
#pragma unroll
            for (int r = 0; r < 4; ++r) {
                int m = m0 + wm + mi * 16 + quad * 4 + r;
                float val = acc[mi][ni][r] + bv;
                if (MODE == 0) {
                    int which = n >> 10;          // 0=Q 1=K 2=V
                    int h  = (n & 1023) >> 6;
                    int dh = n & 63;
                    int bb = m >> 11;
                    int s  = m & 2047;
                    size_t off = (((size_t)bb * H_ + h) * S_ + s) * DH_ + dh;
                    unsigned short* dst = (which == 0) ? q : ((which == 1) ? k : v);
                    dst[off] = f2bf(val);
                } else {
                    out[(size_t)m * N + n] = val;
                }
            }
        }
    }
}

// ---------------------------------------------------------------------------
// Flash-style MFMA attention (validated round 3, unchanged).
// ---------------------------------------------------------------------------
__global__ __launch_bounds__(256) void attn_mfma(
    const unsigned short* __restrict__ q, const unsigned short* __restrict__ k,
    const unsigned short* __restrict__ v, const int* __restrict__ mask,
    unsigned short* __restrict__ ctx)
{
    __shared__ unsigned short Ks[64][72];      // [key][dh]
    __shared__ unsigned short Vt[64][72];      // [dh][key]
    __shared__ unsigned short Ps[4][16][72];   // per-wave P tile [qrow][key]

    const int tid  = threadIdx.x;
    const int wave = tid >> 6;
    const int lane = tid & 63;
    const int col  = lane & 15;
    const int quad = lane >> 4;

    const int h  = blockIdx.y;
    const int bb = blockIdx.z;
    const int q0 = blockIdx.x * 64 + wave * 16;
    const size_t kvbase = ((size_t)bb * H_ + h) * S_ * DH_;

    const unsigned short* qrow = q + kvbase + (size_t)(q0 + col) * DH_;
    short8 qa0 = *(const short8*)(qrow + quad * 8);
    short8 qa1 = *(const short8*)(qrow + 32 + quad * 8);

    size_t mrow[4];
#pragma unroll
    for (int r = 0; r < 4; ++r)
        mrow[r] = ((size_t)bb * S_ + (q0 + quad * 4 + r)) * (size_t)S_;

    float4v oacc[4] = {};
    float m_run[4] = {-3.0e38f, -3.0e38f, -3.0e38f, -3.0e38f};
    float l_run[4] = {0.f, 0.f, 0.f, 0.f};

    for (int kt = 0; kt < S_ / 64; ++kt) {
        const int key0 = kt * 64;

#pragma unroll
        for (int i = 0; i < 4; ++i) {
            int idx = tid + i * 256;
            int r  = idx >> 4;
            int c4 = (idx & 15) * 4;
            ushort4 gk = *(const ushort4*)(k + kvbase + (size_t)(key0 + r) * DH_ + c4);
            *(ushort4*)&Ks[r][c4] = gk;
            ushort4 gv = *(const ushort4*)(v + kvbase + (size_t)(key0 + r) * DH_ + c4);
            Vt[c4 + 0][r] = gv.x; Vt[c4 + 1][r] = gv.y;
            Vt[c4 + 2][r] = gv.z; Vt[c4 + 3][r] = gv.w;
        }
        __syncthreads();

        float4v sc[4];
#pragma unroll
        for (int sub = 0; sub < 4; ++sub) {
            short8 b0 = *(const short8*)&Ks[sub * 16 + col][quad * 8];
            short8 b1 = *(const short8*)&Ks[sub * 16 + col][32 + quad * 8];
            float4v acs = {};
            acs = __builtin_amdgcn_mfma_f32_16x16x32_bf16(qa0, b0, acs, 0, 0, 0);
            acs = __builtin_amdgcn_mfma_f32_16x16x32_bf16(qa1, b1, acs, 0, 0, 0);
            sc[sub] = acs;
        }

#pragma unroll
        for (int sub = 0; sub < 4; ++sub) {
#pragma unroll
            for (int r = 0; r < 4; ++r) {
                float s = sc[sub][r] * 0.125f;
                int mk = mask[mrow[r] + key0 + sub * 16 + col];
                sc[sub][r] = (mk == 0) ? -1000.0f : s;
            }
        }

        float tmax[4];
#pragma unroll
        for (int r = 0; r < 4; ++r) {
            tmax[r] = fmaxf(fmaxf(sc[0][r], sc[1][r]), fmaxf(sc[2][r], sc[3][r]));
#pragma unroll
            for (int msk = 1; msk < 16; msk <<= 1)
                tmax[r] = fmaxf(tmax[r], __shfl_xor(tmax[r], msk));
        }
        float alpha[4], rsum[4];
#pragma unroll
        for (int r = 0; r < 4; ++r) {
            float mn = fmaxf(m_run[r], tmax[r]);
            alpha[r] = __expf(m_run[r] - mn);
            m_run[r] = mn;
            rsum[r] = 0.f;
        }
#pragma unroll
        for (int sub = 0; sub < 4; ++sub) {
#pragma unroll
            for (int r = 0; r < 4; ++r) {
                float p = __expf(sc[sub][r] - m_run[r]);
                rsum[r] += p;
                Ps[wave][quad * 4 + r][sub * 16 + col] = f2bf(p);
            }
        }
#pragma unroll
        for (int r = 0; r < 4; ++r) {
#pragma unroll
            for (int msk = 1; msk < 16; msk <<= 1)
                rsum[r] += __shfl_xor(rsum[r], msk);
            l_run[r] = l_run[r] * alpha[r] + rsum[r];
        }
#pragma unroll
        for (int n = 0; n < 4; ++n)
#pragma unroll
            for (int r = 0; r < 4; ++r)
                oacc[n][r] *= alpha[r];

        __syncthreads();

#pragma unroll
        for (int n = 0; n < 4; ++n) {
#pragma unroll
            for (int kk = 0; kk < 2; ++kk) {
                short8 pa = *(const short8*)&Ps[wave][col][kk * 32 + quad * 8];
                short8 vb = *(const short8*)&Vt[n * 16 + col][kk * 32 + quad * 8];
                oacc[n] = __builtin_amdgcn_mfma_f32_16x16x32_bf16(pa, vb, oacc[n], 0, 0, 0);
            }
        }
        __syncthreads();
    }

    float inv[4];
#pragma unroll
    for (int r = 0; r < 4; ++r) inv[r] = 1.0f / l_run[r];
#pragma unroll
    for (int n = 0; n < 4; ++n) {
#pragma unroll
        for (int r = 0; r < 4; ++r) {
            size_t off = ((size_t)bb * S_ + (q0 + quad * 4 + r)) * D_
                       + h * DH_ + n * 16 + col;
            ctx[off] = f2bf(oacc[n][r] * inv[r]);
        }
    }
}

extern "C" void kernel_launch(void* const* d_in, const int* in_sizes, int n_in,
                              void* d_out, int out_size, void* d_ws, size_t ws_size,
                              hipStream_t stream)
{
    const float* x     = (const float*)d_in[0];
    const int*   mask  = (const int*)d_in[1];
    const float* w_qkv = (const float*)d_in[2];
    const float* b_qkv = (const float*)d_in[3];
    const float* w_out = (const float*)d_in[4];
    const float* b_out = (const float*)d_in[5];
    float* out = (float*)d_out;

    unsigned short* ws = (unsigned short*)d_ws;
    const size_t sz = (size_t)B_ * S_ * D_;   // 8,388,608 elements
    unsigned short* q     = ws;
    unsigned short* kk    = ws + sz;
    unsigned short* v     = ws + 2 * sz;
    unsigned short* ctx   = ws + 3 * sz;
    unsigned short* xbf   = ws + 4 * sz;
    unsigned short* wqkvT = ws + 5 * sz;                       // 3072*1024
    unsigned short* woutT = ws + 5 * sz + (size_t)N3_ * D_;    // 1024*1024

    // pre-pass: bf16 conversions (+ weight transposes)
    convert_x<<<(int)(sz / (256 * 8)), 256, 0, stream>>>(x, xbf, (int)(sz / 8));
    convert_wT<<<dim3(N3_ / 32, D_ / 32), 256, 0, stream>>>(w_qkv, wqkvT, D_, N3_);
    convert_wT<<<dim3(D_ / 32, D_ / 32), 256, 0, stream>>>(w_out, woutT, D_, D_);

    // QKV projection (MFMA) -> q/k/v scatter
    gemm_bt<0><<<dim3(N3_ / 128, (B_ * S_) / 128), 256, 0, stream>>>(
        xbf, wqkvT, b_qkv, q, kk, v, nullptr, D_, N3_);

    // attention
    attn_mfma<<<dim3(S_ / 64, H_, B_), 256, 0, stream>>>(q, kk, v, mask, ctx);

    // output projection (MFMA) -> fp32 out
    gemm_bt<1><<<dim3(D_ / 128, (B_ * S_) / 128), 256, 0, stream>>>(
        ctx, woutT, b_out, nullptr, nullptr, nullptr, out, D_, D_);
}

// Round 5
// 496.661 us; speedup vs baseline: 21.2584x; 1.1151x over previous
//
#include <hip/hip_runtime.h>
#include <hip/hip_bf16.h>
#include <stdint.h>

// Problem constants
#define B_  4
#define S_  2048
#define D_  1024
#define H_  16
#define DH_ 64
#define N3_ 3072   // 3*D

typedef __attribute__((ext_vector_type(8))) short  short8;   // 8 bf16 (4 VGPRs)
typedef __attribute__((ext_vector_type(8))) unsigned short ushort8;
typedef __attribute__((ext_vector_type(4))) float  float4v;  // 4 fp32 acc

__device__ __forceinline__ float bf2f(unsigned short u) {
    union { unsigned int i; float f; } c; c.i = ((unsigned int)u) << 16; return c.f;
}
__device__ __forceinline__ unsigned short f2bf(float f) {
    union { float f; unsigned int i; } c; c.f = f;
    unsigned int x = c.i;
    return (unsigned short)((x + 0x7FFFu + ((x >> 16) & 1u)) >> 16);  // RNE
}
__device__ __forceinline__ unsigned short f2bf_hu(float f) {   // half-up (cheap)
    union { float f; unsigned int i; } c; c.f = f;
    return (unsigned short)((c.i + 0x8000u) >> 16);
}

// ---------------------------------------------------------------------------
// fp32 -> bf16 elementwise (x). 8 elems/thread.
// ---------------------------------------------------------------------------
__global__ __launch_bounds__(256) void convert_x(
    const float* __restrict__ in, unsigned short* __restrict__ out, int n8)
{
    int g = blockIdx.x * 256 + threadIdx.x;
    if (g >= n8) return;
    const float4* p = (const float4*)(in + (size_t)g * 8);
    float4 a = p[0], b = p[1];
    ushort8 o;
    o[0] = f2bf(a.x); o[1] = f2bf(a.y); o[2] = f2bf(a.z); o[3] = f2bf(a.w);
    o[4] = f2bf(b.x); o[5] = f2bf(b.y); o[6] = f2bf(b.z); o[7] = f2bf(b.w);
    *(ushort8*)(out + (size_t)g * 8) = o;
}

// ---------------------------------------------------------------------------
// fp32 [K][N] -> bf16 [N][K] transpose (weights). 32x32 LDS tile, 256 thr.
// ---------------------------------------------------------------------------
__global__ __launch_bounds__(256) void convert_wT(
    const float* __restrict__ w, unsigned short* __restrict__ wt, int K, int N)
{
    __shared__ float t[32][33];
    const int row = threadIdx.x >> 5;   // 0..7
    const int col = threadIdx.x & 31;   // 0..31
    const int n0 = blockIdx.x * 32;
    const int k0 = blockIdx.y * 32;
#pragma unroll
    for (int i = 0; i < 4; ++i)
        t[row + 8 * i][col] = w[(size_t)(k0 + row + 8 * i) * N + n0 + col];
    __syncthreads();
#pragma unroll
    for (int i = 0; i < 4; ++i)
        wt[(size_t)(n0 + row + 8 * i) * K + k0 + col] = f2bf(t[col][row + 8 * i]);
}

// ---------------------------------------------------------------------------
// bf16 MFMA GEMM: C[M,N] = A[M,K] @ Bt[N,K]^T + bias.
// 128x128 tile, BK=64, 256 thr = 4 waves, each wave 64x64 (4x4 MFMA tiles).
// MODE 0: scatter to q/k [B][H][S][DH] and vT [B][H][DH][S] bf16 (N=3072).
// MODE 1: fp32 out [M][N] (N=1024).
// ---------------------------------------------------------------------------
template <int MODE>
__global__ __launch_bounds__(256) void gemm_bt(
    const unsigned short* __restrict__ a, const unsigned short* __restrict__ bt,
    const float* __restrict__ bias,
    unsigned short* __restrict__ q, unsigned short* __restrict__ k,
    unsigned short* __restrict__ v, float* __restrict__ out,
    int K, int N)
{
    __shared__ unsigned short As[128][72];   // pad 64->72 (16B-aligned rows)
    __shared__ unsigned short Bs[128][72];

    const int tid  = threadIdx.x;
    const int wave = tid >> 6;
    const int lane = tid & 63;
    const int col  = lane & 15;
    const int quad = lane >> 4;
    const int wm   = (wave & 1) * 64;
    const int wn   = (wave >> 1) * 64;

    const int m0 = blockIdx.y * 128;
    const int n0 = blockIdx.x * 128;

    float4v acc[4][4] = {};

    for (int kt = 0; kt < K; kt += 64) {
#pragma unroll
        for (int i = 0; i < 4; ++i) {
            int g = tid + i * 256;
            int r = g >> 3;
            int c8 = (g & 7) * 8;
            *(ushort8*)&As[r][c8] = *(const ushort8*)(a  + (size_t)(m0 + r) * K + kt + c8);
            *(ushort8*)&Bs[r][c8] = *(const ushort8*)(bt + (size_t)(n0 + r) * K + kt + c8);
        }
        __syncthreads();

#pragma unroll
        for (int ks = 0; ks < 64; ks += 32) {
            short8 af[4], bf[4];
#pragma unroll
            for (int mi = 0; mi < 4; ++mi)
                af[mi] = *(const short8*)&As[wm + mi * 16 + col][ks + quad * 8];
#pragma unroll
            for (int ni = 0; ni < 4; ++ni)
                bf[ni] = *(const short8*)&Bs[wn + ni * 16 + col][ks + quad * 8];
#pragma unroll
            for (int mi = 0; mi < 4; ++mi)
#pragma unroll
                for (int ni = 0; ni < 4; ++ni)
                    acc[mi][ni] = __builtin_amdgcn_mfma_f32_16x16x32_bf16(
                        af[mi], bf[ni], acc[mi][ni], 0, 0, 0);
        }
        __syncthreads();
    }

#pragma unroll
    for (int mi = 0; mi < 4; ++mi) {
#pragma unroll
        for (int ni = 0; ni < 4; ++ni) {
            int n = n0 + wn + ni * 16 + col;
            float bv = bias[n];
#pragma unroll
            for (int r = 0; r < 4; ++r) {
                int m = m0 + wm + mi * 16 + quad * 4 + r;
                float val = acc[mi][ni][r] + bv;
                if (MODE == 0) {
                    int which = n >> 10;          // 0=Q 1=K 2=V
                    int h  = (n & 1023) >> 6;
                    int dh = n & 63;
                    int bb = m >> 11;
                    int s  = m & 2047;
                    size_t off;
                    if (which == 2)   // V stored transposed: [b][h][dh][s]
                        off = (((size_t)bb * H_ + h) * DH_ + dh) * S_ + s;
                    else
                        off = (((size_t)bb * H_ + h) * S_ + s) * DH_ + dh;
                    unsigned short* dst = (which == 0) ? q : ((which == 1) ? k : v);
                    dst[off] = f2bf(val);
                } else {
                    out[(size_t)m * N + n] = val;
                }
            }
        }
    }
}

// ---------------------------------------------------------------------------
// Flash-style MFMA attention, v2.
// - V arrives pre-transposed (vT[b][h][dh][s]) -> conflict-free b128 staging.
// - Q fragments pre-scaled by 0.125*log2(e): QK^T emits scores in exp2
//   domain; v_exp_f32 is natively 2^x (saves per-element mul).
// - Masked score = -1000*log2(e). P -> bf16 via half-up round (2 ops).
// Fragment layouts (validated in-kernel rounds 3-4):
//   A[m][k]: m=lane&15, k=quad*8+j ; B[k][n]: n=lane&15, k=quad*8+j
//   C/D    : col(n)=lane&15, row(m)=quad*4+reg
// ---------------------------------------------------------------------------
__global__ __launch_bounds__(256) void attn_mfma(
    const unsigned short* __restrict__ q, const unsigned short* __restrict__ k,
    const unsigned short* __restrict__ vT, const int* __restrict__ mask,
    unsigned short* __restrict__ ctx)
{
    __shared__ unsigned short Ks[64][72];      // [key][dh]
    __shared__ unsigned short Vt[64][72];      // [dh][key]
    __shared__ unsigned short Ps[4][16][72];   // per-wave P tile [qrow][key]

    const int tid  = threadIdx.x;
    const int wave = tid >> 6;
    const int lane = tid & 63;
    const int col  = lane & 15;
    const int quad = lane >> 4;

    const int h  = blockIdx.y;
    const int bb = blockIdx.z;
    const int q0 = blockIdx.x * 64 + wave * 16;
    const int kvbase = ((bb * H_ + h) * S_) * DH_;   // < 2^24, int ok
    const int vtbase = ((bb * H_ + h) * DH_) * S_;

    // Q A-frags, pre-scaled by 1/sqrt(DH) * log2(e)
    const float SC = 0.18033688011112042f;   // 0.125 * 1.4426950408889634
    const unsigned short* qrow = q + kvbase + (q0 + col) * DH_;
    ushort8 qr0 = *(const ushort8*)(qrow + quad * 8);
    ushort8 qr1 = *(const ushort8*)(qrow + 32 + quad * 8);
    short8 qa0, qa1;
#pragma unroll
    for (int j = 0; j < 8; ++j) {
        qa0[j] = (short)f2bf(bf2f(qr0[j]) * SC);
        qa1[j] = (short)f2bf(bf2f(qr1[j]) * SC);
    }
    const float MASKED = -1442.6951f;        // -1000 * log2(e)

    int mrow[4];
#pragma unroll
    for (int r = 0; r < 4; ++r)
        mrow[r] = (bb * S_ + (q0 + quad * 4 + r)) * S_;

    float4v oacc[4] = {};
    float m_run[4] = {-3.0e38f, -3.0e38f, -3.0e38f, -3.0e38f};
    float l_run[4] = {0.f, 0.f, 0.f, 0.f};

    for (int kt = 0; kt < S_ / 64; ++kt) {
        const int key0 = kt * 64;

        // ---- stage K [key][dh] and V^T [dh][key]: straight b128 rows ----
#pragma unroll
        for (int i = 0; i < 2; ++i) {
            int g = tid + i * 256;
            int r  = g >> 3;            // Ks: key row / Vt: dh row
            int c8 = (g & 7) * 8;
            *(ushort8*)&Ks[r][c8] = *(const ushort8*)(k  + kvbase + (key0 + r) * DH_ + c8);
            *(ushort8*)&Vt[r][c8] = *(const ushort8*)(vT + vtbase + r * S_ + key0 + c8);
        }
        __syncthreads();

        // ---- QK^T (scores already in exp2 domain) ----
        float4v sc[4];
#pragma unroll
        for (int sub = 0; sub < 4; ++sub) {
            short8 b0 = *(const short8*)&Ks[sub * 16 + col][quad * 8];
            short8 b1 = *(const short8*)&Ks[sub * 16 + col][32 + quad * 8];
            float4v acs = {};
            acs = __builtin_amdgcn_mfma_f32_16x16x32_bf16(qa0, b0, acs, 0, 0, 0);
            acs = __builtin_amdgcn_mfma_f32_16x16x32_bf16(qa1, b1, acs, 0, 0, 0);
            sc[sub] = acs;
        }

        // ---- mask ----
#pragma unroll
        for (int sub = 0; sub < 4; ++sub) {
#pragma unroll
            for (int r = 0; r < 4; ++r) {
                int mk = mask[mrow[r] + key0 + sub * 16 + col];
                sc[sub][r] = (mk == 0) ? MASKED : sc[sub][r];
            }
        }

        // ---- online softmax (exp2 domain) ----
        float tmax[4];
#pragma unroll
        for (int r = 0; r < 4; ++r) {
            tmax[r] = fmaxf(fmaxf(sc[0][r], sc[1][r]), fmaxf(sc[2][r], sc[3][r]));
#pragma unroll
            for (int msk = 1; msk < 16; msk <<= 1)
                tmax[r] = fmaxf(tmax[r], __shfl_xor(tmax[r], msk));
        }
        float alpha[4], rsum[4];
#pragma unroll
        for (int r = 0; r < 4; ++r) {
            float mn = fmaxf(m_run[r], tmax[r]);
            alpha[r] = __builtin_amdgcn_exp2f(m_run[r] - mn);
            m_run[r] = mn;
            rsum[r] = 0.f;
        }
#pragma unroll
        for (int sub = 0; sub < 4; ++sub) {
#pragma unroll
            for (int r = 0; r < 4; ++r) {
                float p = __builtin_amdgcn_exp2f(sc[sub][r] - m_run[r]);
                rsum[r] += p;
                Ps[wave][quad * 4 + r][sub * 16 + col] = f2bf_hu(p);
            }
        }
#pragma unroll
        for (int r = 0; r < 4; ++r) {
#pragma unroll
            for (int msk = 1; msk < 16; msk <<= 1)
                rsum[r] += __shfl_xor(rsum[r], msk);
            l_run[r] = l_run[r] * alpha[r] + rsum[r];
        }
#pragma unroll
        for (int n = 0; n < 4; ++n)
#pragma unroll
            for (int r = 0; r < 4; ++r)
                oacc[n][r] *= alpha[r];

        __syncthreads();   // Ps visible; Ks reads complete

        // ---- PV: O(16x64) += P(16x64) * V(64x64) ----
        short8 pa0 = *(const short8*)&Ps[wave][col][quad * 8];
        short8 pa1 = *(const short8*)&Ps[wave][col][32 + quad * 8];
#pragma unroll
        for (int n = 0; n < 4; ++n) {
            short8 vb0 = *(const short8*)&Vt[n * 16 + col][quad * 8];
            short8 vb1 = *(const short8*)&Vt[n * 16 + col][32 + quad * 8];
            oacc[n] = __builtin_amdgcn_mfma_f32_16x16x32_bf16(pa0, vb0, oacc[n], 0, 0, 0);
            oacc[n] = __builtin_amdgcn_mfma_f32_16x16x32_bf16(pa1, vb1, oacc[n], 0, 0, 0);
        }
        __syncthreads();   // Vt/Ps reads done before restage
    }

    float inv[4];
#pragma unroll
    for (int r = 0; r < 4; ++r) inv[r] = 1.0f / l_run[r];
#pragma unroll
    for (int n = 0; n < 4; ++n) {
#pragma unroll
        for (int r = 0; r < 4; ++r) {
            size_t off = ((size_t)bb * S_ + (q0 + quad * 4 + r)) * D_
                       + h * DH_ + n * 16 + col;
            ctx[off] = f2bf(oacc[n][r] * inv[r]);
        }
    }
}

extern "C" void kernel_launch(void* const* d_in, const int* in_sizes, int n_in,
                              void* d_out, int out_size, void* d_ws, size_t ws_size,
                              hipStream_t stream)
{
    const float* x     = (const float*)d_in[0];
    const int*   mask  = (const int*)d_in[1];
    const float* w_qkv = (const float*)d_in[2];
    const float* b_qkv = (const float*)d_in[3];
    const float* w_out = (const float*)d_in[4];
    const float* b_out = (const float*)d_in[5];
    float* out = (float*)d_out;

    unsigned short* ws = (unsigned short*)d_ws;
    const size_t sz = (size_t)B_ * S_ * D_;   // 8,388,608 elements
    unsigned short* q     = ws;
    unsigned short* kk    = ws + sz;
    unsigned short* v     = ws + 2 * sz;      // vT layout [B][H][DH][S]
    unsigned short* ctx   = ws + 3 * sz;
    unsigned short* xbf   = ws + 4 * sz;
    unsigned short* wqkvT = ws + 5 * sz;                       // 3072*1024
    unsigned short* woutT = ws + 5 * sz + (size_t)N3_ * D_;    // 1024*1024

    convert_x<<<(int)(sz / (256 * 8)), 256, 0, stream>>>(x, xbf, (int)(sz / 8));
    convert_wT<<<dim3(N3_ / 32, D_ / 32), 256, 0, stream>>>(w_qkv, wqkvT, D_, N3_);
    convert_wT<<<dim3(D_ / 32, D_ / 32), 256, 0, stream>>>(w_out, woutT, D_, D_);

    gemm_bt<0><<<dim3(N3_ / 128, (B_ * S_) / 128), 256, 0, stream>>>(
        xbf, wqkvT, b_qkv, q, kk, v, nullptr, D_, N3_);

    attn_mfma<<<dim3(S_ / 64, H_, B_), 256, 0, stream>>>(q, kk, v, mask, ctx);

    gemm_bt<1><<<dim3(D_ / 128, (B_ * S_) / 128), 256, 0, stream>>>(
        ctx, woutT, b_out, nullptr, nullptr, nullptr, out, D_, D_);
}